// Round 1
// baseline (558.924 us; speedup 1.0000x reference)
//
#include <hip/hip_runtime.h>

#define D 128

// ---------------- precompute: degrees, CSR build ----------------

__global__ __launch_bounds__(256) void k_init_deg(float* __restrict__ deg, int n) {
  int i = blockIdx.x * 256 + threadIdx.x;
  if (i < n) deg[i] = 1.0f;  // self-loop weight
}

__global__ __launch_bounds__(256) void k_deg_cnt(const int* __restrict__ dst, const float* __restrict__ ew,
                                                 float* __restrict__ deg, int* __restrict__ cnt, int E) {
  int e = blockIdx.x * 256 + threadIdx.x;
  if (e < E) {
    int d = dst[e];
    atomicAdd(&deg[d], ew[e]);
    atomicAdd(&cnt[d], 1);
  }
}

__global__ __launch_bounds__(256) void k_dis(const float* __restrict__ deg, float* __restrict__ dis, int n) {
  int i = blockIdx.x * 256 + threadIdx.x;
  if (i < n) {
    float dg = deg[i];
    dis[i] = dg > 0.f ? rsqrtf(dg) : 0.f;
  }
}

// single-block exclusive scan of cnt[0..n) -> rowptr[0..n], cursor copy
__global__ __launch_bounds__(1024) void k_scan(const int* __restrict__ cnt, int* __restrict__ rowptr,
                                               int* __restrict__ cursor, int n) {
  __shared__ int sums[1024];
  int tid = threadIdx.x;
  int chunk = (n + 1023) >> 10;
  int beg = tid * chunk;
  int end = min(beg + chunk, n);
  int s = 0;
  for (int i = beg; i < end; ++i) s += cnt[i];
  sums[tid] = s;
  __syncthreads();
  for (int off = 1; off < 1024; off <<= 1) {
    int v = 0;
    if (tid >= off) v = sums[tid - off];
    __syncthreads();
    sums[tid] += v;
    __syncthreads();
  }
  int run = sums[tid] - s;  // exclusive prefix
  for (int i = beg; i < end; ++i) {
    rowptr[i] = run;
    cursor[i] = run;
    run += cnt[i];
  }
  if (end == n && beg < n) rowptr[n] = run;
}

__global__ __launch_bounds__(256) void k_scatter(const int* __restrict__ src, const int* __restrict__ dst,
                                                 const float* __restrict__ ew, const float* __restrict__ dis,
                                                 int* __restrict__ cursor, int* __restrict__ csr_src,
                                                 float* __restrict__ csr_norm, int E) {
  int e = blockIdx.x * 256 + threadIdx.x;
  if (e < E) {
    int s = src[e], d = dst[e];
    int p = atomicAdd(&cursor[d], 1);
    csr_src[p] = s;
    csr_norm[p] = dis[s] * ew[e] * dis[d];
  }
}

// ---------------- per-layer: GEMM (h = z @ W), f32 ----------------
// block = 256 threads, 32 rows x 128 cols; z tile in LDS, W streamed (L2-hot)

__global__ __launch_bounds__(256) void k_gemm(const float* __restrict__ Z, const float* __restrict__ W,
                                              float* __restrict__ H, int n) {
  __shared__ float zs[32 * 128];
  int tid = threadIdx.x;
  int row0 = blockIdx.x * 32;
  const float4* zg = (const float4*)Z;
  float4* zs4 = (float4*)zs;
#pragma unroll
  for (int i = 0; i < 4; ++i) {
    int idx = tid + 256 * i;               // float4 index within tile [0,1024)
    int r = row0 + (idx >> 5);             // 32 float4 per row
    float4 v = make_float4(0.f, 0.f, 0.f, 0.f);
    if (r < n) v = zg[(size_t)row0 * 32 + idx];
    zs4[idx] = v;
  }
  __syncthreads();
  int c = tid & 127;
  int rh = tid >> 7;  // 0 or 1 -> rows [rh*16, rh*16+16)
  float acc[16];
#pragma unroll
  for (int i = 0; i < 16; ++i) acc[i] = 0.f;
  for (int k = 0; k < 128; k += 4) {
    float w0 = W[(k + 0) * 128 + c];
    float w1 = W[(k + 1) * 128 + c];
    float w2 = W[(k + 2) * 128 + c];
    float w3 = W[(k + 3) * 128 + c];
#pragma unroll
    for (int i = 0; i < 16; ++i) {
      float4 z4 = *(const float4*)&zs[(rh * 16 + i) * 128 + k];
      acc[i] = fmaf(z4.x, w0, acc[i]);
      acc[i] = fmaf(z4.y, w1, acc[i]);
      acc[i] = fmaf(z4.z, w2, acc[i]);
      acc[i] = fmaf(z4.w, w3, acc[i]);
    }
  }
#pragma unroll
  for (int i = 0; i < 16; ++i) {
    int r = row0 + rh * 16 + i;
    if (r < n) H[(size_t)r * 128 + c] = acc[i];
  }
}

// ---------------- per-layer: aggregation + bias + relu ----------------
// one wave per node; lane handles features {2*lane, 2*lane+1}

__global__ __launch_bounds__(256) void k_agg(const float* __restrict__ H, const int* __restrict__ rowptr,
                                             const int* __restrict__ csr_src, const float* __restrict__ csr_norm,
                                             const float* __restrict__ dis, const float* __restrict__ bias,
                                             float* __restrict__ out, int n) {
  int node = blockIdx.x * 4 + (threadIdx.x >> 6);
  if (node >= n) return;
  int lane = threadIdx.x & 63;
  const float2* h2 = (const float2*)H;
  float dn = dis[node];
  float sn = dn * dn;  // self-loop norm = 1/deg
  float2 hv = h2[(size_t)node * 64 + lane];
  float ax = hv.x * sn, ay = hv.y * sn;
  int e = rowptr[node], end = rowptr[node + 1];
  for (; e + 2 <= end; e += 2) {
    int s0 = csr_src[e];     float w0 = csr_norm[e];
    int s1 = csr_src[e + 1]; float w1 = csr_norm[e + 1];
    float2 h0 = h2[(size_t)s0 * 64 + lane];
    float2 h1 = h2[(size_t)s1 * 64 + lane];
    ax = fmaf(h0.x, w0, ax); ay = fmaf(h0.y, w0, ay);
    ax = fmaf(h1.x, w1, ax); ay = fmaf(h1.y, w1, ay);
  }
  if (e < end) {
    int s0 = csr_src[e]; float w0 = csr_norm[e];
    float2 h0 = h2[(size_t)s0 * 64 + lane];
    ax = fmaf(h0.x, w0, ax); ay = fmaf(h0.y, w0, ay);
  }
  float2 bv = ((const float2*)bias)[lane];
  ax = fmaxf(ax + bv.x, 0.f);
  ay = fmaxf(ay + bv.y, 0.f);
  float2 o; o.x = ax; o.y = ay;
  ((float2*)out)[(size_t)node * 64 + lane] = o;
}

// ---------------- host ----------------

extern "C" void kernel_launch(void* const* d_in, const int* in_sizes, int n_in,
                              void* d_out, int out_size, void* d_ws, size_t ws_size,
                              hipStream_t stream) {
  const float* x  = (const float*)d_in[0];
  const int*   ei = (const int*)d_in[1];   // int32: [2, E] row-major
  const float* ew = (const float*)d_in[2];
  const float* Wl[3] = {(const float*)d_in[3], (const float*)d_in[5], (const float*)d_in[7]};
  const float* bl[3] = {(const float*)d_in[4], (const float*)d_in[6], (const float*)d_in[8]};

  const int n = in_sizes[0] / D;
  const int E = in_sizes[1] / 2;
  const int* src = ei;
  const int* dst = ei + E;

  char* p = (char*)d_ws;
  float* Z        = (float*)p; p += (size_t)n * D * 4;
  float* H        = (float*)p; p += (size_t)n * D * 4;
  float* deg      = (float*)p; p += (size_t)n * 4;
  float* dis      = (float*)p; p += (size_t)n * 4;
  int*   cnt      = (int*)p;   p += (size_t)n * 4;
  int*   cursor   = (int*)p;   p += (size_t)n * 4;
  int*   rowptr   = (int*)p;   p += (size_t)(n + 1) * 4;
  int*   csr_src  = (int*)p;   p += (size_t)E * 4;
  float* csr_norm = (float*)p; p += (size_t)E * 4;
  (void)ws_size; (void)n_in;

  const int gb = (n + 255) / 256;
  const int ge = (E + 255) / 256;

  hipMemsetAsync(cnt, 0, (size_t)n * 4, stream);
  k_init_deg<<<gb, 256, 0, stream>>>(deg, n);
  k_deg_cnt<<<ge, 256, 0, stream>>>(dst, ew, deg, cnt, E);
  k_dis<<<gb, 256, 0, stream>>>(deg, dis, n);
  k_scan<<<1, 1024, 0, stream>>>(cnt, rowptr, cursor, n);
  k_scatter<<<ge, 256, 0, stream>>>(src, dst, ew, dis, cursor, csr_src, csr_norm, E);

  const float* zin = x;
  float* outp = (float*)d_out;
  for (int l = 0; l < 3; ++l) {
    k_gemm<<<(n + 31) / 32, 256, 0, stream>>>(zin, Wl[l], H, n);
    float* zo = (l == 2) ? outp : Z;
    k_agg<<<(n + 3) / 4, 256, 0, stream>>>(H, rowptr, csr_src, csr_norm, dis, bl[l], zo, n);
    zin = Z;
  }
}

// Round 2
// 425.593 us; speedup vs baseline: 1.3133x; 1.3133x over previous
//
#include <hip/hip_runtime.h>

#define D 128

// ---------------- precompute: degrees, CSR build ----------------

__global__ __launch_bounds__(256) void k_init(float* __restrict__ deg, int* __restrict__ cnt, int n) {
  int i = blockIdx.x * 256 + threadIdx.x;
  if (i < n) { deg[i] = 1.0f; cnt[i] = 0; }  // self-loop weight; zero histogram
}

__global__ __launch_bounds__(256) void k_deg_cnt(const int* __restrict__ dst, const float* __restrict__ ew,
                                                 float* __restrict__ deg, int* __restrict__ cnt, int E) {
  int e = blockIdx.x * 256 + threadIdx.x;
  if (e < E) {
    int d = dst[e];
    atomicAdd(&deg[d], ew[e]);
    atomicAdd(&cnt[d], 1);
  }
}

// scan pass A: per-block (256 elems) sums
__global__ __launch_bounds__(256) void k_blocksum(const int* __restrict__ cnt, int* __restrict__ bsum, int n) {
  int i = blockIdx.x * 256 + threadIdx.x;
  int v = (i < n) ? cnt[i] : 0;
#pragma unroll
  for (int off = 32; off > 0; off >>= 1) v += __shfl_down(v, off);
  __shared__ int ws[4];
  if ((threadIdx.x & 63) == 0) ws[threadIdx.x >> 6] = v;
  __syncthreads();
  if (threadIdx.x == 0) bsum[blockIdx.x] = ws[0] + ws[1] + ws[2] + ws[3];
}

// scan pass B: exclusive scan of block sums (nb <= 256), single block
__global__ __launch_bounds__(256) void k_scanb(const int* __restrict__ bsum, int* __restrict__ boff, int nb) {
  __shared__ int s[256];
  int t = threadIdx.x;
  int v = (t < nb) ? bsum[t] : 0;
  s[t] = v;
  __syncthreads();
#pragma unroll
  for (int off = 1; off < 256; off <<= 1) {
    int u = (t >= off) ? s[t - off] : 0;
    __syncthreads();
    s[t] += u;
    __syncthreads();
  }
  if (t < nb) boff[t] = s[t] - v;  // exclusive
}

// scan pass C: block-local exclusive scan + global offset -> rowptr, cursor; also dis = rsqrt(deg)
__global__ __launch_bounds__(256) void k_scanc(const int* __restrict__ cnt, const int* __restrict__ boff,
                                               const float* __restrict__ deg, float* __restrict__ dis,
                                               int* __restrict__ rowptr, int* __restrict__ cursor,
                                               int n, int Etot) {
  __shared__ int s[256];
  int t = threadIdx.x;
  int i = blockIdx.x * 256 + t;
  int v = (i < n) ? cnt[i] : 0;
  s[t] = v;
  __syncthreads();
#pragma unroll
  for (int off = 1; off < 256; off <<= 1) {
    int u = (t >= off) ? s[t - off] : 0;
    __syncthreads();
    s[t] += u;
    __syncthreads();
  }
  int ex = s[t] - v + boff[blockIdx.x];
  if (i < n) {
    rowptr[i] = ex;
    cursor[i] = ex;
    float dg = deg[i];
    dis[i] = dg > 0.f ? rsqrtf(dg) : 0.f;
  }
  if (i == 0) rowptr[n] = Etot;
}

__global__ __launch_bounds__(256) void k_scatter(const int* __restrict__ src, const int* __restrict__ dst,
                                                 const float* __restrict__ ew, const float* __restrict__ dis,
                                                 int* __restrict__ cursor, float2* __restrict__ csr, int E) {
  int e = blockIdx.x * 256 + threadIdx.x;
  if (e < E) {
    int s = src[e], d = dst[e];
    int p = atomicAdd(&cursor[d], 1);
    float2 rec;
    rec.x = __int_as_float(s);
    rec.y = dis[s] * ew[e] * dis[d];
    csr[p] = rec;
  }
}

// ---------------- per-layer: GEMM (h = z @ W), f32 ----------------
// block = 256 threads, tile 32 rows x 128 cols; per-thread 8 rows x 2 cols.
// z tile in LDS (broadcast reads, conflict-free); W streamed float2 (L2-hot).

__global__ __launch_bounds__(256) void k_gemm(const float* __restrict__ Z, const float* __restrict__ W,
                                              float* __restrict__ H, int n) {
  __shared__ float zs[32 * 128];
  int tid = threadIdx.x;
  int row0 = blockIdx.x * 32;
  const float4* zg = (const float4*)Z;
  float4* zs4 = (float4*)zs;
#pragma unroll
  for (int i = 0; i < 4; ++i) {
    int idx = tid + 256 * i;               // float4 index within tile [0,1024)
    int r = row0 + (idx >> 5);             // 32 float4 per row
    float4 v = make_float4(0.f, 0.f, 0.f, 0.f);
    if (r < n) v = zg[(size_t)row0 * 32 + idx];
    zs4[idx] = v;
  }
  __syncthreads();
  int c2 = tid & 63;   // columns {2*c2, 2*c2+1}
  int r8 = tid >> 6;   // rows [r8*8, r8*8+8)
  const float2* W2 = (const float2*)W;
  float accx[8], accy[8];
#pragma unroll
  for (int i = 0; i < 8; ++i) { accx[i] = 0.f; accy[i] = 0.f; }
  for (int k = 0; k < 128; k += 4) {
    float2 w0 = W2[(size_t)(k + 0) * 64 + c2];
    float2 w1 = W2[(size_t)(k + 1) * 64 + c2];
    float2 w2 = W2[(size_t)(k + 2) * 64 + c2];
    float2 w3 = W2[(size_t)(k + 3) * 64 + c2];
#pragma unroll
    for (int i = 0; i < 8; ++i) {
      float4 z4 = *(const float4*)&zs[(r8 * 8 + i) * 128 + k];
      accx[i] = fmaf(z4.x, w0.x, accx[i]); accy[i] = fmaf(z4.x, w0.y, accy[i]);
      accx[i] = fmaf(z4.y, w1.x, accx[i]); accy[i] = fmaf(z4.y, w1.y, accy[i]);
      accx[i] = fmaf(z4.z, w2.x, accx[i]); accy[i] = fmaf(z4.z, w2.y, accy[i]);
      accx[i] = fmaf(z4.w, w3.x, accx[i]); accy[i] = fmaf(z4.w, w3.y, accy[i]);
    }
  }
  float2* H2 = (float2*)H;
#pragma unroll
  for (int i = 0; i < 8; ++i) {
    int r = row0 + r8 * 8 + i;
    if (r < n) H2[(size_t)r * 64 + c2] = make_float2(accx[i], accy[i]);
  }
}

// ---------------- per-layer: aggregation + bias + relu ----------------
// one wave per node; lane handles features {2*lane, 2*lane+1}

__global__ __launch_bounds__(256) void k_agg(const float* __restrict__ H, const int* __restrict__ rowptr,
                                             const float2* __restrict__ csr, const float* __restrict__ dis,
                                             const float* __restrict__ bias, float* __restrict__ out, int n) {
  int node = blockIdx.x * 4 + (threadIdx.x >> 6);
  if (node >= n) return;
  int lane = threadIdx.x & 63;
  const float2* h2 = (const float2*)H;
  float dn = dis[node];
  float sn = dn * dn;  // self-loop norm = 1/deg
  float2 hv = h2[(size_t)node * 64 + lane];
  float ax = hv.x * sn, ay = hv.y * sn;
  int e = rowptr[node], end = rowptr[node + 1];
  for (; e + 2 <= end; e += 2) {
    float2 r0 = csr[e];
    float2 r1 = csr[e + 1];
    int s0 = __float_as_int(r0.x); float w0 = r0.y;
    int s1 = __float_as_int(r1.x); float w1 = r1.y;
    float2 h0 = h2[(size_t)s0 * 64 + lane];
    float2 h1 = h2[(size_t)s1 * 64 + lane];
    ax = fmaf(h0.x, w0, ax); ay = fmaf(h0.y, w0, ay);
    ax = fmaf(h1.x, w1, ax); ay = fmaf(h1.y, w1, ay);
  }
  if (e < end) {
    float2 r0 = csr[e];
    int s0 = __float_as_int(r0.x); float w0 = r0.y;
    float2 h0 = h2[(size_t)s0 * 64 + lane];
    ax = fmaf(h0.x, w0, ax); ay = fmaf(h0.y, w0, ay);
  }
  float2 bv = ((const float2*)bias)[lane];
  ax = fmaxf(ax + bv.x, 0.f);
  ay = fmaxf(ay + bv.y, 0.f);
  ((float2*)out)[(size_t)node * 64 + lane] = make_float2(ax, ay);
}

// ---------------- host ----------------

extern "C" void kernel_launch(void* const* d_in, const int* in_sizes, int n_in,
                              void* d_out, int out_size, void* d_ws, size_t ws_size,
                              hipStream_t stream) {
  const float* x  = (const float*)d_in[0];
  const int*   ei = (const int*)d_in[1];   // int32: [2, E] row-major
  const float* ew = (const float*)d_in[2];
  const float* Wl[3] = {(const float*)d_in[3], (const float*)d_in[5], (const float*)d_in[7]};
  const float* bl[3] = {(const float*)d_in[4], (const float*)d_in[6], (const float*)d_in[8]};

  const int n = in_sizes[0] / D;
  const int E = in_sizes[1] / 2;
  const int* src = ei;
  const int* dst = ei + E;

  char* p = (char*)d_ws;
  float*  Z      = (float*)p;  p += (size_t)n * D * 4;
  float*  H      = (float*)p;  p += (size_t)n * D * 4;
  float*  deg    = (float*)p;  p += (size_t)n * 4;
  float*  dis    = (float*)p;  p += (size_t)n * 4;
  int*    cnt    = (int*)p;    p += (size_t)n * 4;
  int*    cursor = (int*)p;    p += (size_t)n * 4;
  int*    rowptr = (int*)p;    p += (size_t)(n + 1) * 4;
  int*    bsum   = (int*)p;    p += 256 * 4;
  int*    boff   = (int*)p;    p += 256 * 4;
  float2* csr    = (float2*)p; p += (size_t)E * 8;
  (void)ws_size; (void)n_in;

  const int gb = (n + 255) / 256;   // 196 blocks over nodes
  const int ge = (E + 255) / 256;

  k_init<<<gb, 256, 0, stream>>>(deg, cnt, n);
  k_deg_cnt<<<ge, 256, 0, stream>>>(dst, ew, deg, cnt, E);
  k_blocksum<<<gb, 256, 0, stream>>>(cnt, bsum, n);
  k_scanb<<<1, 256, 0, stream>>>(bsum, boff, gb);
  k_scanc<<<gb, 256, 0, stream>>>(cnt, boff, deg, dis, rowptr, cursor, n, E);
  k_scatter<<<ge, 256, 0, stream>>>(src, dst, ew, dis, cursor, csr, E);

  const float* zin = x;
  float* outp = (float*)d_out;
  for (int l = 0; l < 3; ++l) {
    k_gemm<<<(n + 31) / 32, 256, 0, stream>>>(zin, Wl[l], H, n);
    float* zo = (l == 2) ? outp : Z;
    k_agg<<<(n + 3) / 4, 256, 0, stream>>>(H, rowptr, csr, dis, bl[l], zo, n);
    zin = Z;
  }
}

// Round 3
// 363.626 us; speedup vs baseline: 1.5371x; 1.1704x over previous
//
#include <hip/hip_runtime.h>

#define D 128

// ---------------- precompute: CSR build with ONE atomic per edge ----------------

__global__ __launch_bounds__(256) void k_init(int* __restrict__ cnt, int n) {
  int i = blockIdx.x * 256 + threadIdx.x;
  if (i < n) cnt[i] = 0;
}

// fused histogram + within-row rank: one int atomic per edge
__global__ __launch_bounds__(256) void k_rank(const int* __restrict__ dst, int* __restrict__ cnt,
                                              int* __restrict__ p_local, int E) {
  int e = blockIdx.x * 256 + threadIdx.x;
  if (e < E) p_local[e] = atomicAdd(&cnt[dst[e]], 1);
}

// scan pass A: per-block (256 elems) sums
__global__ __launch_bounds__(256) void k_blocksum(const int* __restrict__ cnt, int* __restrict__ bsum, int n) {
  int i = blockIdx.x * 256 + threadIdx.x;
  int v = (i < n) ? cnt[i] : 0;
#pragma unroll
  for (int off = 32; off > 0; off >>= 1) v += __shfl_down(v, off);
  __shared__ int ws[4];
  if ((threadIdx.x & 63) == 0) ws[threadIdx.x >> 6] = v;
  __syncthreads();
  if (threadIdx.x == 0) bsum[blockIdx.x] = ws[0] + ws[1] + ws[2] + ws[3];
}

// scan pass B: exclusive scan of block sums (nb <= 256), single block
__global__ __launch_bounds__(256) void k_scanb(const int* __restrict__ bsum, int* __restrict__ boff, int nb) {
  __shared__ int s[256];
  int t = threadIdx.x;
  int v = (t < nb) ? bsum[t] : 0;
  s[t] = v;
  __syncthreads();
#pragma unroll
  for (int off = 1; off < 256; off <<= 1) {
    int u = (t >= off) ? s[t - off] : 0;
    __syncthreads();
    s[t] += u;
    __syncthreads();
  }
  if (t < nb) boff[t] = s[t] - v;  // exclusive
}

// scan pass C: block-local exclusive scan + global offset -> rowptr
__global__ __launch_bounds__(256) void k_scanc(const int* __restrict__ cnt, const int* __restrict__ boff,
                                               int* __restrict__ rowptr, int n, int Etot) {
  __shared__ int s[256];
  int t = threadIdx.x;
  int i = blockIdx.x * 256 + t;
  int v = (i < n) ? cnt[i] : 0;
  s[t] = v;
  __syncthreads();
#pragma unroll
  for (int off = 1; off < 256; off <<= 1) {
    int u = (t >= off) ? s[t - off] : 0;
    __syncthreads();
    s[t] += u;
    __syncthreads();
  }
  int ex = s[t] - v + boff[blockIdx.x];
  if (i < n) rowptr[i] = ex;
  if (i == 0) rowptr[n] = Etot;
}

// atomic-free scatter: pos = rowptr[dst] + p_local ; csr = {src_bits, ew}
__global__ __launch_bounds__(256) void k_scatter(const int* __restrict__ src, const int* __restrict__ dst,
                                                 const float* __restrict__ ew, const int* __restrict__ rowptr,
                                                 const int* __restrict__ p_local, float2* __restrict__ csr, int E) {
  int e = blockIdx.x * 256 + threadIdx.x;
  if (e < E) {
    int d = dst[e];
    int pos = rowptr[d] + p_local[e];
    float2 rec;
    rec.x = __int_as_float(src[e]);
    rec.y = ew[e];
    csr[pos] = rec;
  }
}

// wave per node: deg = 1 + sum(ew over row); dis = rsqrt(deg)
__global__ __launch_bounds__(256) void k_degdis(const float2* __restrict__ csr, const int* __restrict__ rowptr,
                                                float* __restrict__ dis, int n) {
  int node = blockIdx.x * 4 + (threadIdx.x >> 6);
  if (node >= n) return;
  int lane = threadIdx.x & 63;
  int beg = rowptr[node], end = rowptr[node + 1];
  float s = 0.f;
  for (int e = beg + lane; e < end; e += 64) s += csr[e].y;
#pragma unroll
  for (int off = 32; off > 0; off >>= 1) s += __shfl_down(s, off);
  if (lane == 0) {
    float dg = 1.0f + s;
    dis[node] = dg > 0.f ? rsqrtf(dg) : 0.f;
  }
}

// fold dis[src] into csr.y (dis[dst] is applied per-node inside k_agg)
__global__ __launch_bounds__(256) void k_norm(float2* __restrict__ csr, const float* __restrict__ dis, int E) {
  int e = blockIdx.x * 256 + threadIdx.x;
  if (e < E) {
    float2 rec = csr[e];
    rec.y *= dis[__float_as_int(rec.x)];
    csr[e] = rec;
  }
}

// ---------------- per-layer: GEMM (h = z @ W), f32 ----------------
// block = 256 threads, tile 32 rows x 128 cols; per-thread 8 rows x 2 cols.

__global__ __launch_bounds__(256) void k_gemm(const float* __restrict__ Z, const float* __restrict__ W,
                                              float* __restrict__ H, int n) {
  __shared__ float zs[32 * 128];
  int tid = threadIdx.x;
  int row0 = blockIdx.x * 32;
  const float4* zg = (const float4*)Z;
  float4* zs4 = (float4*)zs;
#pragma unroll
  for (int i = 0; i < 4; ++i) {
    int idx = tid + 256 * i;               // float4 index within tile [0,1024)
    int r = row0 + (idx >> 5);             // 32 float4 per row
    float4 v = make_float4(0.f, 0.f, 0.f, 0.f);
    if (r < n) v = zg[(size_t)row0 * 32 + idx];
    zs4[idx] = v;
  }
  __syncthreads();
  int c2 = tid & 63;   // columns {2*c2, 2*c2+1}
  int r8 = tid >> 6;   // rows [r8*8, r8*8+8)
  const float2* W2 = (const float2*)W;
  float accx[8], accy[8];
#pragma unroll
  for (int i = 0; i < 8; ++i) { accx[i] = 0.f; accy[i] = 0.f; }
  for (int k = 0; k < 128; k += 4) {
    float2 w0 = W2[(size_t)(k + 0) * 64 + c2];
    float2 w1 = W2[(size_t)(k + 1) * 64 + c2];
    float2 w2 = W2[(size_t)(k + 2) * 64 + c2];
    float2 w3 = W2[(size_t)(k + 3) * 64 + c2];
#pragma unroll
    for (int i = 0; i < 8; ++i) {
      float4 z4 = *(const float4*)&zs[(r8 * 8 + i) * 128 + k];
      accx[i] = fmaf(z4.x, w0.x, accx[i]); accy[i] = fmaf(z4.x, w0.y, accy[i]);
      accx[i] = fmaf(z4.y, w1.x, accx[i]); accy[i] = fmaf(z4.y, w1.y, accy[i]);
      accx[i] = fmaf(z4.z, w2.x, accx[i]); accy[i] = fmaf(z4.z, w2.y, accy[i]);
      accx[i] = fmaf(z4.w, w3.x, accx[i]); accy[i] = fmaf(z4.w, w3.y, accy[i]);
    }
  }
  float2* H2 = (float2*)H;
#pragma unroll
  for (int i = 0; i < 8; ++i) {
    int r = row0 + r8 * 8 + i;
    if (r < n) H2[(size_t)r * 64 + c2] = make_float2(accx[i], accy[i]);
  }
}

// ---------------- per-layer: aggregation + bias + relu ----------------
// 32-lane group per node; lane holds float4 (4 features); 2-edge unroll.
// out = dis[n] * sum_e (dis[src]*ew)*h[src]  +  dis[n]^2 * h[n]  + b, relu

__global__ __launch_bounds__(256) void k_agg(const float* __restrict__ H, const int* __restrict__ rowptr,
                                             const float2* __restrict__ csr, const float* __restrict__ dis,
                                             const float* __restrict__ bias, float* __restrict__ out, int n) {
  int node = blockIdx.x * 8 + (threadIdx.x >> 5);
  if (node >= n) return;
  int l32 = threadIdx.x & 31;
  const float4* h4 = (const float4*)H;
  float4 acc = make_float4(0.f, 0.f, 0.f, 0.f);
  int e = rowptr[node], end = rowptr[node + 1];
  for (; e + 2 <= end; e += 2) {
    float2 r0 = csr[e];
    float2 r1 = csr[e + 1];
    int s0 = __float_as_int(r0.x); float w0 = r0.y;
    int s1 = __float_as_int(r1.x); float w1 = r1.y;
    float4 h0 = h4[(size_t)s0 * 32 + l32];
    float4 h1 = h4[(size_t)s1 * 32 + l32];
    acc.x = fmaf(h0.x, w0, acc.x); acc.y = fmaf(h0.y, w0, acc.y);
    acc.z = fmaf(h0.z, w0, acc.z); acc.w = fmaf(h0.w, w0, acc.w);
    acc.x = fmaf(h1.x, w1, acc.x); acc.y = fmaf(h1.y, w1, acc.y);
    acc.z = fmaf(h1.z, w1, acc.z); acc.w = fmaf(h1.w, w1, acc.w);
  }
  if (e < end) {
    float2 r0 = csr[e];
    int s0 = __float_as_int(r0.x); float w0 = r0.y;
    float4 h0 = h4[(size_t)s0 * 32 + l32];
    acc.x = fmaf(h0.x, w0, acc.x); acc.y = fmaf(h0.y, w0, acc.y);
    acc.z = fmaf(h0.z, w0, acc.z); acc.w = fmaf(h0.w, w0, acc.w);
  }
  float dn = dis[node];
  float sn = dn * dn;
  float4 hv = h4[(size_t)node * 32 + l32];
  float4 bv = ((const float4*)bias)[l32];
  float4 o;
  o.x = fmaxf(fmaf(dn, acc.x, fmaf(sn, hv.x, bv.x)), 0.f);
  o.y = fmaxf(fmaf(dn, acc.y, fmaf(sn, hv.y, bv.y)), 0.f);
  o.z = fmaxf(fmaf(dn, acc.z, fmaf(sn, hv.z, bv.z)), 0.f);
  o.w = fmaxf(fmaf(dn, acc.w, fmaf(sn, hv.w, bv.w)), 0.f);
  ((float4*)out)[(size_t)node * 32 + l32] = o;
}

// ---------------- host ----------------

extern "C" void kernel_launch(void* const* d_in, const int* in_sizes, int n_in,
                              void* d_out, int out_size, void* d_ws, size_t ws_size,
                              hipStream_t stream) {
  const float* x  = (const float*)d_in[0];
  const int*   ei = (const int*)d_in[1];   // int32: [2, E] row-major
  const float* ew = (const float*)d_in[2];
  const float* Wl[3] = {(const float*)d_in[3], (const float*)d_in[5], (const float*)d_in[7]};
  const float* bl[3] = {(const float*)d_in[4], (const float*)d_in[6], (const float*)d_in[8]};

  const int n = in_sizes[0] / D;
  const int E = in_sizes[1] / 2;
  const int* src = ei;
  const int* dst = ei + E;

  char* p = (char*)d_ws;
  float*  Z       = (float*)p;  p += (size_t)n * D * 4;
  float*  H       = (float*)p;  p += (size_t)n * D * 4;
  float*  dis     = (float*)p;  p += (size_t)n * 4;
  int*    cnt     = (int*)p;    p += (size_t)n * 4;
  int*    rowptr  = (int*)p;    p += (size_t)(n + 1) * 4;
  int*    bsum    = (int*)p;    p += 256 * 4;
  int*    boff    = (int*)p;    p += 256 * 4;
  int*    p_local = (int*)p;    p += (size_t)E * 4;
  float2* csr     = (float2*)p; p += (size_t)E * 8;
  (void)ws_size; (void)n_in;

  const int gb = (n + 255) / 256;   // blocks over nodes
  const int ge = (E + 255) / 256;   // blocks over edges

  k_init<<<gb, 256, 0, stream>>>(cnt, n);
  k_rank<<<ge, 256, 0, stream>>>(dst, cnt, p_local, E);
  k_blocksum<<<gb, 256, 0, stream>>>(cnt, bsum, n);
  k_scanb<<<1, 256, 0, stream>>>(bsum, boff, gb);
  k_scanc<<<gb, 256, 0, stream>>>(cnt, boff, rowptr, n, E);
  k_scatter<<<ge, 256, 0, stream>>>(src, dst, ew, rowptr, p_local, csr, E);
  k_degdis<<<(n + 3) / 4, 256, 0, stream>>>(csr, rowptr, dis, n);
  k_norm<<<ge, 256, 0, stream>>>(csr, dis, E);

  const float* zin = x;
  float* outp = (float*)d_out;
  for (int l = 0; l < 3; ++l) {
    k_gemm<<<(n + 31) / 32, 256, 0, stream>>>(zin, Wl[l], H, n);
    float* zo = (l == 2) ? outp : Z;
    k_agg<<<(n + 7) / 8, 256, 0, stream>>>(H, rowptr, csr, dis, bl[l], zo, n);
    zin = Z;
  }
}